// Round 2
// baseline (450.494 us; speedup 1.0000x reference)
//
#include <hip/hip_runtime.h>

// GNN, fixed shapes: B=128 graphs x N=64 nodes, D=64 features, M=8192, HL=3, OL=2.
// adjacency [8192x8192] f32 is block-diagonal (128 diagonal 64x64 blocks), entries
// exactly 0.0/1.0, each block SYMMETRIC. All float tensors f32; fingerprints int32.
//
// ONE persistent kernel, 256 blocks (ALL 256 CUs, 1 block/CU co-resident):
// each graph is split across 2 sibling blocks by feature-column half (32 cols each).
// Per MP layer a block computes its 32 columns of h = selu(xW^T+b) and
// y = x + A@h (needs full x / full A / half W — all block-local), contributes its
// columns' BN stats via global atomics, writes its raw y-half to a double-buffered
// global exchange buffer, crosses the grid barrier, then reads the sibling half and
// normalizes the full x locally. Head (2-layer MLP + BN over 128 graphs + proj) is
// row-local per graph; sibling half==0 owns the stats contribution and the output.
// 5 grid barriers total (3 MP + 2 head); barrier's release-acquire chain orders the
// exchange-buffer stores (standard cooperative-grid pattern).
#define MT   8192
#define DD   64
#define NPG  64
#define NGRAPH 128
#define NBLK 256
#define XP   68          // xsc column stride (floats)
#define WP   33          // wT row stride (32 cols + 1 pad)
#define HP   34          // hs row stride (32 cols + 2 pad)
#define XGSZ (NGRAPH * DD * NPG)   // one exchange buffer: 524288 floats (2 MB)
#define BN_EPS 1e-5f

__device__ __forceinline__ float selu_f(float x) {
  const float scale = 1.0507009873554804934f;
  const float alpha = 1.6732632423543772848f;
  return x > 0.f ? scale * x : scale * alpha * (__expf(x) - 1.f);
}

// Device-scope grid barrier (generation counter). All 256 blocks co-resident
// (1 block/CU on 256 CUs, ~44KB LDS), so spinning is safe.
__device__ __forceinline__ void gbar(int* cnt, int* gen) {
  __syncthreads();
  if (threadIdx.x == 0) {
    int g = __hip_atomic_load(gen, __ATOMIC_RELAXED, __HIP_MEMORY_SCOPE_AGENT);
    int a = __hip_atomic_fetch_add(cnt, 1, __ATOMIC_ACQ_REL, __HIP_MEMORY_SCOPE_AGENT);
    if (a == (int)gridDim.x - 1) {
      __hip_atomic_store(cnt, 0, __ATOMIC_RELAXED, __HIP_MEMORY_SCOPE_AGENT);
      __hip_atomic_store(gen, g + 1, __ATOMIC_RELEASE, __HIP_MEMORY_SCOPE_AGENT);
    } else {
      while (__hip_atomic_load(gen, __ATOMIC_ACQUIRE, __HIP_MEMORY_SCOPE_AGENT) == g)
        __builtin_amdgcn_s_sleep(1);
    }
  }
  __syncthreads();
}

__global__ __launch_bounds__(256) void gnn_k(
    const int* __restrict__ fpr,
    const float* __restrict__ emb,     // [NFP,64]
    const float* __restrict__ adj,     // [8192,8192] block-diagonal 0/1
    const float* __restrict__ Wf,      // [3,64,64]
    const float* __restrict__ bfv,     // [3,64]
    const float* __restrict__ Wo,      // [2,64,64]
    const float* __restrict__ bo,      // [2,64]
    const float* __restrict__ Wp,      // [64]
    const float* __restrict__ bp,      // [1]
    float* __restrict__ out,           // [128] final output
    float* __restrict__ stats,         // [5*128] zeroed (sum|sumsq per BN)
    float* __restrict__ xg,            // [2][128][64][64] exchange (no zero needed)
    int* __restrict__ bar)             // [2] zeroed (cnt, gen)
{
  __shared__ float xsc[XP * 64];          // FULL x col-major: xsc[d*XP + n]
  __shared__ float wT[64 * WP];           // this half's W^T: wT[k*WP + c], c in [0,32)
  __shared__ float hs[64 * HP];           // this half's h: hs[n*HP + c]
  __shared__ unsigned char aU[64 * 64];   // full A block bytes, aU[r*64 + k]
  __shared__ float red1[16 * 32], red2[16 * 32];
  __shared__ float mus[64], rss[64];
  __shared__ float mvec[64];              // pooled mol row of this graph

  const int tid  = threadIdx.x;
  const int bid  = blockIdx.x;
  const int b    = bid >> 1;              // graph
  const int half = bid & 1;               // feature-column half
  const int C0   = half * 32;             // this block's column base
  const int S0   = 32 - C0;               // sibling's column base
  const int tr = tid >> 4, tc = tid & 15;
  const int n0 = tr * 4, c0 = tc * 2;     // output tile: 4 nodes x 2 cols

  // ---- stage full A block (bytes) + full x (embed gather, col-major) ----
  for (int j = 0; j < 4; ++j) {
    int e = (tid + j * 256) * 4;
    int r = e >> 6, k = e & 63;
    float4 av = *(const float4*)(adj + (size_t)(b * NPG + r) * MT + b * NPG + k);
    uchar4 u;
    u.x = (unsigned char)av.x; u.y = (unsigned char)av.y;
    u.z = (unsigned char)av.z; u.w = (unsigned char)av.w;
    *(uchar4*)(aU + e) = u;
    int f = fpr[b * NPG + r];
    float4 xv = *(const float4*)(emb + (size_t)f * DD + k);
    xsc[(k + 0) * XP + r] = xv.x;
    xsc[(k + 1) * XP + r] = xv.y;
    xsc[(k + 2) * XP + r] = xv.z;
    xsc[(k + 3) * XP + r] = xv.w;
  }
  // ---- stage this half's W^T for layer 0 (rows C0..C0+31) ----
  for (int j = 0; j < 2; ++j) {
    int q4 = (tid + j * 256) * 4;          // 0..2047
    int cc = q4 >> 6, k = q4 & 63;         // cc in [0,32)
    float4 wv = *(const float4*)(Wf + (size_t)(C0 + cc) * DD + k);
    wT[(k + 0) * WP + cc] = wv.x;
    wT[(k + 1) * WP + cc] = wv.y;
    wT[(k + 2) * WP + cc] = wv.z;
    wT[(k + 3) * WP + cc] = wv.w;
  }
  __syncthreads();

  float poolp = 0.f;

  for (int l = 0; l < 3; ++l) {
    float* xgb = xg + (size_t)(l & 1) * XGSZ;   // double-buffered exchange

    // ---- GEMM1: h[:,C0+c] = selu(x @ W^T + b), this half's 32 cols ----
    {
      float acc[4][2] = {};
#pragma unroll 4
      for (int d = 0; d < DD; ++d) {
        float4 xv = *(const float4*)(xsc + d * XP + n0);
        float2 wv = *(const float2*)(wT + d * WP + c0);
#pragma unroll
        for (int i = 0; i < 4; ++i) {
          float xk = ((const float*)&xv)[i];
          acc[i][0] += xk * wv.x;
          acc[i][1] += xk * wv.y;
        }
      }
      float b2x = bfv[l * DD + C0 + c0];
      float b2y = bfv[l * DD + C0 + c0 + 1];
#pragma unroll
      for (int i = 0; i < 4; ++i) {
        float2 hv;
        hv.x = selu_f(acc[i][0] + b2x);
        hv.y = selu_f(acc[i][1] + b2y);
        *(float2*)(hs + (n0 + i) * HP + c0) = hv;
      }
    }
    __syncthreads();   // hs ready

    // Prefetch next layer's W half into registers (latency hides under GEMM2+barrier)
    float4 wreg[2];
    if (l < 2) {
#pragma unroll
      for (int j = 0; j < 2; ++j) {
        int q4 = (tid + j * 256) * 4;
        int cc = q4 >> 6, k = q4 & 63;
        wreg[j] = *(const float4*)(Wf + (size_t)(l + 1) * 4096 + (size_t)(C0 + cc) * DD + k);
      }
    }

    // ---- GEMM2: y[:,c] = x[:,c] + A @ h[:,c] (A via symmetry: aU[k*64+n]=A[n][k]) ----
    {
      float acc[4][2] = {};
#pragma unroll 4
      for (int k = 0; k < DD; ++k) {
        uchar4 a4 = *(const uchar4*)(aU + k * DD + n0);
        float2 hv = *(const float2*)(hs + k * HP + c0);
        float af[4] = { (float)a4.x, (float)a4.y, (float)a4.z, (float)a4.w };
#pragma unroll
        for (int i = 0; i < 4; ++i) {
          acc[i][0] += af[i] * hv.x;
          acc[i][1] += af[i] * hv.y;
        }
      }
      // residual + xsc update (own cols) + exchange write + stat partials
#pragma unroll
      for (int ci = 0; ci < 2; ++ci) {
        int c = c0 + ci;                       // local col in [0,32)
        float* p = xsc + (C0 + c) * XP + n0;
        float4 xo = *(const float4*)p;
        float y0 = acc[0][ci] + xo.x;
        float y1 = acc[1][ci] + xo.y;
        float y2 = acc[2][ci] + xo.z;
        float y3 = acc[3][ci] + xo.w;
        float4 yv = { y0, y1, y2, y3 };
        *(float4*)p = yv;
        *(float4*)(xgb + ((size_t)(b * DD + C0 + c)) * NPG + n0) = yv;  // raw y half
        red1[tr * 32 + c] = y0 + y1 + y2 + y3;
        red2[tr * 32 + c] = y0 * y0 + y1 * y1 + y2 * y2 + y3 * y3;
      }
    }
    __syncthreads();
    // column reduce (this half's 32 columns): tid<32 sums, tid in [32,64) sumsqs
    if (tid < 32) {
      float t1 = 0.f;
#pragma unroll
      for (int q = 0; q < 16; ++q) t1 += red1[q * 32 + tid];
      atomicAdd(&stats[l * 128 + C0 + tid], t1);
    } else if (tid < 64) {
      int c = tid - 32;
      float t2 = 0.f;
#pragma unroll
      for (int q = 0; q < 16; ++q) t2 += red2[q * 32 + c];
      atomicAdd(&stats[l * 128 + DD + C0 + c], t2);
    }
    // restage wT from prefetched registers (wT dead since GEMM1)
    if (l < 2) {
#pragma unroll
      for (int j = 0; j < 2; ++j) {
        int q4 = (tid + j * 256) * 4;
        int cc = q4 >> 6, k = q4 & 63;
        wT[(k + 0) * WP + cc] = wreg[j].x;
        wT[(k + 1) * WP + cc] = wreg[j].y;
        wT[(k + 2) * WP + cc] = wreg[j].z;
        wT[(k + 3) * WP + cc] = wreg[j].w;
      }
    }

    gbar(bar, bar + 1);   // batch-global BN stats complete; xg halves visible

    if (tid < DD) {
      float s1 = __hip_atomic_load(&stats[l * 128 + tid], __ATOMIC_RELAXED,
                                   __HIP_MEMORY_SCOPE_AGENT);
      float s2 = __hip_atomic_load(&stats[l * 128 + DD + tid], __ATOMIC_RELAXED,
                                   __HIP_MEMORY_SCOPE_AGENT);
      float mu  = s1 * (1.f / MT);
      float var = fmaxf(s2 * (1.f / MT) - mu * mu, 0.f);
      mus[tid] = mu;
      rss[tid] = rsqrtf(var + BN_EPS);
    }
    // pull sibling's raw y half into xsc (old values there are dead)
#pragma unroll
    for (int ci = 0; ci < 2; ++ci) {
      int c = c0 + ci;
      float4 v = *(const float4*)(xgb + ((size_t)(b * DD + S0 + c)) * NPG + n0);
      *(float4*)(xsc + (S0 + c) * XP + n0) = v;
    }
    __syncthreads();

    // ---- normalize full x in place; thread owns column d=tid>>2, quarter q ----
    {
      int d = tid >> 2, q = tid & 3;
      float mu = mus[d], rs = rss[d];
      float* p = xsc + d * XP + q * 16;
      float ps = 0.f;
#pragma unroll
      for (int w = 0; w < 4; ++w) {
        float4 v = *(const float4*)(p + w * 4);
        v.x = (v.x - mu) * rs; v.y = (v.y - mu) * rs;
        v.z = (v.z - mu) * rs; v.w = (v.w - mu) * rs;
        *(float4*)(p + w * 4) = v;
        ps += v.x + v.y + v.z + v.w;
      }
      poolp = ps;
    }
    if (l == 2) red1[tid] = poolp;   // pooling partials (red1 free)
    __syncthreads();
  }

  // ---- pool: mean over the 64 nodes of this graph -> mvec ----
  if (tid < DD)
    mvec[tid] = (red1[tid * 4] + red1[tid * 4 + 1] + red1[tid * 4 + 2] + red1[tid * 4 + 3])
                * (1.f / NPG);

  // ---- fused output MLP head: row-local; BN stats global over 128 graphs ----
  // wTo overlays xsc (dead): 64*65 = 4160 <= 4352.
  float* wTo = xsc;
  float hn = 0.f;
  for (int j = 0; j < 2; ++j) {
    for (int q = 0; q < 16; ++q) {
      int e = tid + q * 256;
      wTo[(e & 63) * 65 + (e >> 6)] = Wo[j * 4096 + e];
    }
    __syncthreads();
    float h = 0.f;
    if (tid < DD) {
      float acc = bo[j * DD + tid];
#pragma unroll 8
      for (int k = 0; k < DD; ++k)
        acc += mvec[k] * wTo[k * 65 + tid];
      h = selu_f(acc);
      if (half == 0) {                       // sibling would double-count
        atomicAdd(&stats[(3 + j) * 128 + tid], h);
        atomicAdd(&stats[(3 + j) * 128 + DD + tid], h * h);
      }
    }
    gbar(bar, bar + 1);   // head BN stats complete (over 128 graph rows)
    if (tid < DD) {
      float s1 = __hip_atomic_load(&stats[(3 + j) * 128 + tid], __ATOMIC_RELAXED,
                                   __HIP_MEMORY_SCOPE_AGENT);
      float s2 = __hip_atomic_load(&stats[(3 + j) * 128 + DD + tid], __ATOMIC_RELAXED,
                                   __HIP_MEMORY_SCOPE_AGENT);
      float mu  = s1 * (1.f / NGRAPH);
      float var = fmaxf(s2 * (1.f / NGRAPH) - mu * mu, 0.f);
      hn = (h - mu) * rsqrtf(var + BN_EPS);
      if (j == 0) mvec[tid] = hn;   // feed next head layer (ordered by next stage+sync)
    }
  }

  // ---- final projection: out[b] = dot(hn_row, Wp) + bp ----
  if (tid < DD) {
    float p = hn * Wp[tid];
#pragma unroll
    for (int o = 32; o; o >>= 1) p += __shfl_down(p, o, 64);
    if (tid == 0 && half == 0) out[b] = p + bp[0];
  }
}

extern "C" void kernel_launch(void* const* d_in, const int* in_sizes, int n_in,
                              void* d_out, int out_size, void* d_ws, size_t ws_size,
                              hipStream_t stream) {
  (void)in_sizes; (void)n_in; (void)out_size; (void)ws_size;
  const int*   fpr = (const int*)d_in[0];
  const float* adj = (const float*)d_in[1];
  const float* emb = (const float*)d_in[2];
  const float* Wf  = (const float*)d_in[3];
  const float* bfv = (const float*)d_in[4];
  const float* Wo  = (const float*)d_in[5];
  const float* bo  = (const float*)d_in[6];
  const float* Wp  = (const float*)d_in[7];
  const float* bp  = (const float*)d_in[8];

  float* ws    = (float*)d_ws;
  float* stats = ws;                 // 5*128 floats (3 MP + 2 head BN stats)
  int*   bar   = (int*)(ws + 640);   // 2 ints (cnt, gen)
  float* xg    = ws + 1024;          // 2 x 524288 floats exchange (4 MB)

  hipMemsetAsync(ws, 0, (640 + 2) * sizeof(float), stream);

  gnn_k<<<NBLK, 256, 0, stream>>>(fpr, emb, adj, Wf, bfv, Wo, bo, Wp, bp,
                                  (float*)d_out, stats, xg, bar);
}

// Round 3
// 365.127 us; speedup vs baseline: 1.2338x; 1.2338x over previous
//
#include <hip/hip_runtime.h>

// GNN, fixed shapes: B=128 graphs x N=64 nodes, D=64 features, M=8192, HL=3, OL=2.
// adjacency [8192x8192] f32 is block-diagonal (128 diagonal 64x64 blocks), entries
// exactly 0.0/1.0, each block SYMMETRIC. All float tensors f32; fingerprints int32.
//
// ONE persistent kernel, 128 blocks x 256 threads (1 block/CU, trivially
// co-resident): embed-gather + 3 message-passing layers + pooling + 2-layer MLP
// head + projection. BatchNorm stats are batch-global -> device-scope grid
// barrier per BN (5 total).
//
// Sync redesign (round 3): the round-1 barrier put cnt and gen on ONE cacheline;
// 128 spinning ACQUIRE readers vs 128 serialized fetch_adds on the same line made
// each barrier ~20us (evidence: fusing away a ~45us head kernel in exchange for
// 2 extra barriers was net 0). Now:
//  - gen isolated on its own line (read-only-shared spin target)
//  - two-level arrival tree: 8 XCD-local group counters (grp = bid&7 matches
//    round-robin XCD dispatch), 256B apart, then one root counter
//  - phase-versioned counters (a == g*16+15 -> group-last): no resets on the
//    release path
//  - BN stats sharded into per-group slots (16-deep XCD-local atomic chains,
//    not 128-deep global ones); post-barrier each block sums the 8 partials.
#define MT   8192
#define DD   64
#define NPG  64
#define NGRAPH 128
#define NBLK 128
#define NG   8           // barrier/stat groups (one per XCD under round-robin)
#define GSZ  16          // blocks per group
#define XP   68          // padded column stride (floats) for xsc/wT
#define BN_EPS 1e-5f

__device__ __forceinline__ float selu_f(float x) {
  const float scale = 1.0507009873554804934f;
  const float alpha = 1.6732632423543772848f;
  return x > 0.f ? scale * x : scale * alpha * (__expf(x) - 1.f);
}

// Two-level grid barrier. bb points to an int region:
//   bb[grp*64]        : per-group arrival counters (one 256B line each)
//   bb[NG*64]         : root counter
//   bb[(NG+1)*64]     : generation (isolated line, spin target)
// Counters are phase-versioned (never reset): at generation g, group-last is
// arrival a == g*GSZ+GSZ-1, root-last is r == g*NG+NG-1.
__device__ __forceinline__ void gbar(int* bb, int grp) {
  __syncthreads();
  if (threadIdx.x == 0) {
    int* gcnt = bb + grp * 64;
    int* rcnt = bb + NG * 64;
    int* gen  = bb + (NG + 1) * 64;
    int g = __hip_atomic_load(gen, __ATOMIC_RELAXED, __HIP_MEMORY_SCOPE_AGENT);
    int a = __hip_atomic_fetch_add(gcnt, 1, __ATOMIC_ACQ_REL, __HIP_MEMORY_SCOPE_AGENT);
    if (a == g * GSZ + (GSZ - 1)) {
      int r = __hip_atomic_fetch_add(rcnt, 1, __ATOMIC_ACQ_REL, __HIP_MEMORY_SCOPE_AGENT);
      if (r == g * NG + (NG - 1)) {
        __hip_atomic_store(gen, g + 1, __ATOMIC_RELEASE, __HIP_MEMORY_SCOPE_AGENT);
      } else {
        while (__hip_atomic_load(gen, __ATOMIC_ACQUIRE, __HIP_MEMORY_SCOPE_AGENT) <= g)
          __builtin_amdgcn_s_sleep(2);
      }
    } else {
      while (__hip_atomic_load(gen, __ATOMIC_ACQUIRE, __HIP_MEMORY_SCOPE_AGENT) <= g)
        __builtin_amdgcn_s_sleep(2);
    }
  }
  __syncthreads();
}

__global__ __launch_bounds__(256) void gnn_k(
    const int* __restrict__ fpr,
    const float* __restrict__ emb,     // [NFP,64]
    const float* __restrict__ adj,     // [8192,8192] block-diagonal 0/1
    const float* __restrict__ Wf,      // [3,64,64]
    const float* __restrict__ bfv,     // [3,64]
    const float* __restrict__ Wo,      // [2,64,64]
    const float* __restrict__ bo,      // [2,64]
    const float* __restrict__ Wp,      // [64]
    const float* __restrict__ bp,      // [1]
    float* __restrict__ out,           // [128] final output
    float* __restrict__ gstats,        // [5][NG][128] zeroed (sum|sumsq shards)
    int* __restrict__ bar)             // [(NG+2)*64] zeroed
{
  __shared__ float xsc[XP * 64];          // x column-major: xsc[d*XP + n]
  __shared__ float wT[XP * 64];           // wT[k*XP + c] = W[c][k]
  __shared__ float hs[64 * 64];           // h row-major: hs[n*64 + d]
  __shared__ unsigned char aU[64 * 64];   // A block bytes, aU[r*64 + k]
  __shared__ float mus[64], rss[64];
  __shared__ float red1[16 * 64], red2[16 * 64];
  __shared__ float mvec[64];              // pooled mol row of this graph

  const int tid = threadIdx.x, b = blockIdx.x;
  const int grp = b & (NG - 1);           // XCD-local under round-robin dispatch
  const int tr = tid >> 4, tc = tid & 15;
  const int n0 = tr * 4, c0 = tc * 4;

  // ---- stage A block (bytes), W^T(layer0), x (embed gather, col-major) ----
  for (int j = 0; j < 4; ++j) {
    int e = (tid + j * 256) * 4;
    int r = e >> 6, k = e & 63;
    float4 av = *(const float4*)(adj + (size_t)(b * NPG + r) * MT + b * NPG + k);
    uchar4 u;
    u.x = (unsigned char)av.x; u.y = (unsigned char)av.y;
    u.z = (unsigned char)av.z; u.w = (unsigned char)av.w;
    *(uchar4*)(aU + e) = u;
    float4 wv = *(const float4*)(Wf + e);          // W[r][k..k+3]
    wT[(k + 0) * XP + r] = wv.x;
    wT[(k + 1) * XP + r] = wv.y;
    wT[(k + 2) * XP + r] = wv.z;
    wT[(k + 3) * XP + r] = wv.w;
    int f = fpr[b * NPG + r];
    float4 xv = *(const float4*)(emb + (size_t)f * DD + k);
    xsc[(k + 0) * XP + r] = xv.x;
    xsc[(k + 1) * XP + r] = xv.y;
    xsc[(k + 2) * XP + r] = xv.z;
    xsc[(k + 3) * XP + r] = xv.w;
  }
  __syncthreads();

  float poolp = 0.f;   // this thread's pooling partial (layer 2)

  for (int l = 0; l < 3; ++l) {
    // ---- GEMM1: h = selu(x @ W^T + b) ----
    {
      float acc[4][4] = {};
#pragma unroll 4
      for (int d = 0; d < DD; ++d) {
        float4 xv = *(const float4*)(xsc + d * XP + n0);
        float4 wv = *(const float4*)(wT + d * XP + c0);
#pragma unroll
        for (int i = 0; i < 4; ++i) {
          float xk = ((const float*)&xv)[i];
          acc[i][0] += xk * wv.x;
          acc[i][1] += xk * wv.y;
          acc[i][2] += xk * wv.z;
          acc[i][3] += xk * wv.w;
        }
      }
      float b4[4];
#pragma unroll
      for (int c = 0; c < 4; ++c) b4[c] = bfv[l * DD + c0 + c];
#pragma unroll
      for (int i = 0; i < 4; ++i) {
        float4 hv;
        hv.x = selu_f(acc[i][0] + b4[0]);
        hv.y = selu_f(acc[i][1] + b4[1]);
        hv.z = selu_f(acc[i][2] + b4[2]);
        hv.w = selu_f(acc[i][3] + b4[3]);
        *(float4*)(hs + (n0 + i) * DD + c0) = hv;
      }
    }
    __syncthreads();   // hs ready

    // Prefetch next layer's W into registers (latency hides under GEMM2+barrier)
    float4 wreg[4];
    if (l < 2) {
#pragma unroll
      for (int j = 0; j < 4; ++j)
        wreg[j] = *(const float4*)(Wf + (size_t)(l + 1) * 4096 + (size_t)(tid + j * 256) * 4);
    }

    // ---- GEMM2: y = x + A @ h (A via symmetry: aU[k*64+n] = A[n][k]) ----
    {
      float acc[4][4] = {};
#pragma unroll 4
      for (int k = 0; k < DD; ++k) {
        uchar4 a4 = *(const uchar4*)(aU + k * DD + n0);
        float4 hv = *(const float4*)(hs + k * DD + c0);
        float af[4] = { (float)a4.x, (float)a4.y, (float)a4.z, (float)a4.w };
#pragma unroll
        for (int i = 0; i < 4; ++i) {
          acc[i][0] += af[i] * hv.x;
          acc[i][1] += af[i] * hv.y;
          acc[i][2] += af[i] * hv.z;
          acc[i][3] += af[i] * hv.w;
        }
      }
      // residual + in-place update of xsc (own cells only) + column stat partials
#pragma unroll
      for (int c = 0; c < 4; ++c) {
        float* p = xsc + (c0 + c) * XP + n0;
        float4 xo = *(const float4*)p;
        float y0 = acc[0][c] + xo.x;
        float y1 = acc[1][c] + xo.y;
        float y2 = acc[2][c] + xo.z;
        float y3 = acc[3][c] + xo.w;
        float4 yv = { y0, y1, y2, y3 };
        *(float4*)p = yv;
        red1[tr * DD + c0 + c] = y0 + y1 + y2 + y3;
        red2[tr * DD + c0 + c] = y0 * y0 + y1 * y1 + y2 * y2 + y3 * y3;
      }
    }
    __syncthreads();
    // column reduce -> per-GROUP stat shard (16-deep XCD-local atomic chains)
    if (tid < DD) {
      float t1 = 0.f;
#pragma unroll
      for (int q = 0; q < 16; ++q) t1 += red1[q * DD + tid];
      atomicAdd(&gstats[((size_t)l * NG + grp) * 128 + tid], t1);
    } else if (tid < 2 * DD) {
      int c = tid - DD;
      float t2 = 0.f;
#pragma unroll
      for (int q = 0; q < 16; ++q) t2 += red2[q * DD + c];
      atomicAdd(&gstats[((size_t)l * NG + grp) * 128 + DD + c], t2);
    }
    // restage wT from prefetched registers (wT dead since GEMM1)
    if (l < 2) {
#pragma unroll
      for (int j = 0; j < 4; ++j) {
        int e = (tid + j * 256) * 4;
        int r = e >> 6, k = e & 63;
        wT[(k + 0) * XP + r] = wreg[j].x;
        wT[(k + 1) * XP + r] = wreg[j].y;
        wT[(k + 2) * XP + r] = wreg[j].z;
        wT[(k + 3) * XP + r] = wreg[j].w;
      }
    }

    gbar(bar, grp);   // batch-global BN stats complete

    if (tid < DD) {
      float s1 = 0.f, s2 = 0.f;
#pragma unroll
      for (int g = 0; g < NG; ++g) {
        const float* p = gstats + ((size_t)l * NG + g) * 128;
        s1 += p[tid];
        s2 += p[DD + tid];
      }
      float mu  = s1 * (1.f / MT);
      float var = fmaxf(s2 * (1.f / MT) - mu * mu, 0.f);
      mus[tid] = mu;
      rss[tid] = rsqrtf(var + BN_EPS);
    }
    __syncthreads();

    // ---- normalize xsc in place; thread owns column d = tid>>2, quarter q ----
    {
      int d = tid >> 2, q = tid & 3;
      float mu = mus[d], rs = rss[d];
      float* p = xsc + d * XP + q * 16;
      float ps = 0.f;
#pragma unroll
      for (int w = 0; w < 4; ++w) {
        float4 v = *(const float4*)(p + w * 4);
        v.x = (v.x - mu) * rs; v.y = (v.y - mu) * rs;
        v.z = (v.z - mu) * rs; v.w = (v.w - mu) * rs;
        *(float4*)(p + w * 4) = v;
        ps += v.x + v.y + v.z + v.w;
      }
      poolp = ps;
    }
    if (l == 2) red1[tid] = poolp;   // pooling partials
    __syncthreads();
  }

  // ---- pool: mean over the 64 nodes of this graph -> mvec ----
  if (tid < DD)
    mvec[tid] = (red1[tid * 4] + red1[tid * 4 + 1] + red1[tid * 4 + 2] + red1[tid * 4 + 3])
                * (1.f / NPG);

  // ---- fused output MLP head: mol row is block-local; BN stats global ----
  // wTo overlays xsc (dead): 64*65 = 4160 <= 4352.
  float* wTo = xsc;
  float hn = 0.f;
  for (int j = 0; j < 2; ++j) {
    for (int q = 0; q < 16; ++q) {
      int e = tid + q * 256;
      wTo[(e & 63) * 65 + (e >> 6)] = Wo[j * 4096 + e];
    }
    __syncthreads();
    float h = 0.f;
    if (tid < DD) {
      float acc = bo[j * DD + tid];
#pragma unroll 8
      for (int k = 0; k < DD; ++k)
        acc += mvec[k] * wTo[k * 65 + tid];
      h = selu_f(acc);
      atomicAdd(&gstats[((size_t)(3 + j) * NG + grp) * 128 + tid], h);
      atomicAdd(&gstats[((size_t)(3 + j) * NG + grp) * 128 + DD + tid], h * h);
    }
    gbar(bar, grp);   // head BN stats complete (over 128 graph rows)
    if (tid < DD) {
      float s1 = 0.f, s2 = 0.f;
#pragma unroll
      for (int g = 0; g < NG; ++g) {
        const float* p = gstats + ((size_t)(3 + j) * NG + g) * 128;
        s1 += p[tid];
        s2 += p[DD + tid];
      }
      float mu  = s1 * (1.f / NGRAPH);
      float var = fmaxf(s2 * (1.f / NGRAPH) - mu * mu, 0.f);
      hn = (h - mu) * rsqrtf(var + BN_EPS);
      if (j == 0) mvec[tid] = hn;   // feed next head layer (ordered by next stage+sync)
    }
  }

  // ---- final projection: out[b] = dot(hn_row, Wp) + bp ----
  if (tid < DD) {
    float p = hn * Wp[tid];
#pragma unroll
    for (int o = 32; o; o >>= 1) p += __shfl_down(p, o, 64);
    if (tid == 0) out[b] = p + bp[0];
  }
}

extern "C" void kernel_launch(void* const* d_in, const int* in_sizes, int n_in,
                              void* d_out, int out_size, void* d_ws, size_t ws_size,
                              hipStream_t stream) {
  (void)in_sizes; (void)n_in; (void)out_size; (void)ws_size;
  const int*   fpr = (const int*)d_in[0];
  const float* adj = (const float*)d_in[1];
  const float* emb = (const float*)d_in[2];
  const float* Wf  = (const float*)d_in[3];
  const float* bfv = (const float*)d_in[4];
  const float* Wo  = (const float*)d_in[5];
  const float* bo  = (const float*)d_in[6];
  const float* Wp  = (const float*)d_in[7];
  const float* bp  = (const float*)d_in[8];

  float* ws     = (float*)d_ws;
  float* gstats = ws;                       // 5*NG*128 = 5120 floats
  int*   bar    = (int*)(ws + 5120);        // (NG+2)*64 = 640 ints

  hipMemsetAsync(ws, 0, (5120 + 640) * sizeof(float), stream);

  gnn_k<<<NBLK, 256, 0, stream>>>(fpr, emb, adj, Wf, bfv, Wo, bo, Wp, bp,
                                  (float*)d_out, gstats, bar);
}

// Round 5
// 360.346 us; speedup vs baseline: 1.2502x; 1.0133x over previous
//
#include <hip/hip_runtime.h>

// GNN, fixed shapes: B=128 graphs x N=64 nodes, D=64 features, M=8192, HL=3, OL=2.
// adjacency [8192x8192] f32 is block-diagonal (128 diagonal 64x64 blocks), entries
// exactly 0.0/1.0, each block SYMMETRIC. All float tensors f32; fingerprints int32.
//
// ONE persistent kernel, 128 blocks x 256 threads (1 block/CU, trivially
// co-resident): embed-gather + 3 message-passing layers + pooling + 2-layer MLP
// head + projection. BatchNorm stats are batch-global -> device-scope grid
// barrier per BN (5 total, structurally irreducible: each BN gates the next op).
//
// Barrier evolution (budget model: dur = 2x160us harness poison fills + ~45us):
//   r1: cnt+gen on ONE line -> ~20us/barrier (RMW storm vs 128 acquire spinners)
//   r3: two-level tree, gen isolated -> ~3-4us/barrier (16+8 serialized RMWs)
//   r5 (this): FLAG ARRAY -> zero serialized RMWs. Block b release-stores phase
//       to its own 128B-spaced flag line; 128 threads/block each acquire-poll one
//       distinct flag. Arrival fully parallel; expected ~1-1.5us/barrier.
// BN stats stay sharded per-group (grp = bid&7, XCD-local atomic chains, 16-deep);
// post-barrier every block redundantly sums the 8 shard partials (parallel loads).
#define MT   8192
#define DD   64
#define NPG  64
#define NGRAPH 128
#define NBLK 128
#define NG   8           // stat shards (one per XCD under round-robin dispatch)
#define FS   32          // flag stride in ints (128B line each)
#define XP   68          // padded column stride (floats) for xsc/wT
#define BN_EPS 1e-5f

__device__ __forceinline__ float selu_f(float x) {
  const float scale = 1.0507009873554804934f;
  const float alpha = 1.6732632423543772848f;
  return x > 0.f ? scale * x : scale * alpha * (__expf(x) - 1.f);
}

// Flag-array grid barrier, phase-versioned (no resets). flags[b*FS] holds the
// last phase block b arrived at. All prior device-scope atomic stat writes are
// drained before the release store, so acquiring any flag >= phase makes that
// block's stats visible.
__device__ __forceinline__ void gbar(int* flags, int phase) {
  __syncthreads();
  if (threadIdx.x == 0)
    __hip_atomic_store(flags + (size_t)blockIdx.x * FS, phase,
                       __ATOMIC_RELEASE, __HIP_MEMORY_SCOPE_AGENT);
  if (threadIdx.x < NBLK) {
    const int* f = flags + (size_t)threadIdx.x * FS;
    while (__hip_atomic_load(f, __ATOMIC_ACQUIRE, __HIP_MEMORY_SCOPE_AGENT) < phase)
      __builtin_amdgcn_s_sleep(1);
  }
  __syncthreads();
}

__global__ __launch_bounds__(256) void gnn_k(
    const int* __restrict__ fpr,
    const float* __restrict__ emb,     // [NFP,64]
    const float* __restrict__ adj,     // [8192,8192] block-diagonal 0/1
    const float* __restrict__ Wf,      // [3,64,64]
    const float* __restrict__ bfv,     // [3,64]
    const float* __restrict__ Wo,      // [2,64,64]
    const float* __restrict__ bo,      // [2,64]
    const float* __restrict__ Wp,      // [64]
    const float* __restrict__ bp,      // [1]
    float* __restrict__ out,           // [128] final output
    float* __restrict__ gstats,        // [5][NG][128] zeroed (sum|sumsq shards)
    int* __restrict__ flags)           // [NBLK*FS] zeroed
{
  __shared__ float xsc[XP * 64];          // x column-major: xsc[d*XP + n]
  __shared__ float wT[XP * 64];           // wT[k*XP + c] = W[c][k]
  __shared__ float hs[64 * 64];           // h row-major: hs[n*64 + d]
  __shared__ unsigned char aU[64 * 64];   // A block bytes, aU[r*64 + k]
  __shared__ float mus[64], rss[64];
  __shared__ float red1[16 * 64], red2[16 * 64];
  __shared__ float mvec[64];              // pooled mol row of this graph

  const int tid = threadIdx.x, b = blockIdx.x;
  const int grp = b & (NG - 1);           // XCD-local under round-robin dispatch
  const int tr = tid >> 4, tc = tid & 15;
  const int n0 = tr * 4, c0 = tc * 4;

  float4 wreg[4];      // register prefetch buffer (next Wf, then head Wo[0])

  // ---- stage A block (bytes), W^T(layer0), x (embed gather, col-major) ----
  for (int j = 0; j < 4; ++j) {
    int e = (tid + j * 256) * 4;
    int r = e >> 6, k = e & 63;
    float4 av = *(const float4*)(adj + (size_t)(b * NPG + r) * MT + b * NPG + k);
    uchar4 u;
    u.x = (unsigned char)av.x; u.y = (unsigned char)av.y;
    u.z = (unsigned char)av.z; u.w = (unsigned char)av.w;
    *(uchar4*)(aU + e) = u;
    float4 wv = *(const float4*)(Wf + e);          // W[r][k..k+3]
    wT[(k + 0) * XP + r] = wv.x;
    wT[(k + 1) * XP + r] = wv.y;
    wT[(k + 2) * XP + r] = wv.z;
    wT[(k + 3) * XP + r] = wv.w;
    int f = fpr[b * NPG + r];
    float4 xv = *(const float4*)(emb + (size_t)f * DD + k);
    xsc[(k + 0) * XP + r] = xv.x;
    xsc[(k + 1) * XP + r] = xv.y;
    xsc[(k + 2) * XP + r] = xv.z;
    xsc[(k + 3) * XP + r] = xv.w;
  }
  __syncthreads();

  float poolp = 0.f;   // this thread's pooling partial (layer 2)

  for (int l = 0; l < 3; ++l) {
    // ---- GEMM1: h = selu(x @ W^T + b) ----
    {
      float acc[4][4] = {};
#pragma unroll 4
      for (int d = 0; d < DD; ++d) {
        float4 xv = *(const float4*)(xsc + d * XP + n0);
        float4 wv = *(const float4*)(wT + d * XP + c0);
#pragma unroll
        for (int i = 0; i < 4; ++i) {
          float xk = ((const float*)&xv)[i];
          acc[i][0] += xk * wv.x;
          acc[i][1] += xk * wv.y;
          acc[i][2] += xk * wv.z;
          acc[i][3] += xk * wv.w;
        }
      }
      float b4[4];
#pragma unroll
      for (int c = 0; c < 4; ++c) b4[c] = bfv[l * DD + c0 + c];
#pragma unroll
      for (int i = 0; i < 4; ++i) {
        float4 hv;
        hv.x = selu_f(acc[i][0] + b4[0]);
        hv.y = selu_f(acc[i][1] + b4[1]);
        hv.z = selu_f(acc[i][2] + b4[2]);
        hv.w = selu_f(acc[i][3] + b4[3]);
        *(float4*)(hs + (n0 + i) * DD + c0) = hv;
      }
    }
    __syncthreads();   // hs ready

    // Prefetch into registers (latency hides under GEMM2 + barrier):
    //   l<2  -> next MP layer's Wf
    //   l==2 -> head layer 0's Wo (consumed after pooling)
    {
      const float* src = (l < 2) ? (Wf + (size_t)(l + 1) * 4096) : Wo;
#pragma unroll
      for (int j = 0; j < 4; ++j)
        wreg[j] = *(const float4*)(src + (size_t)(tid + j * 256) * 4);
    }

    // ---- GEMM2: y = x + A @ h (A via symmetry: aU[k*64+n] = A[n][k]) ----
    {
      float acc[4][4] = {};
#pragma unroll 4
      for (int k = 0; k < DD; ++k) {
        uchar4 a4 = *(const uchar4*)(aU + k * DD + n0);
        float4 hv = *(const float4*)(hs + k * DD + c0);
        float af[4] = { (float)a4.x, (float)a4.y, (float)a4.z, (float)a4.w };
#pragma unroll
        for (int i = 0; i < 4; ++i) {
          acc[i][0] += af[i] * hv.x;
          acc[i][1] += af[i] * hv.y;
          acc[i][2] += af[i] * hv.z;
          acc[i][3] += af[i] * hv.w;
        }
      }
      // residual + in-place update of xsc (own cells only) + column stat partials
#pragma unroll
      for (int c = 0; c < 4; ++c) {
        float* p = xsc + (c0 + c) * XP + n0;
        float4 xo = *(const float4*)p;
        float y0 = acc[0][c] + xo.x;
        float y1 = acc[1][c] + xo.y;
        float y2 = acc[2][c] + xo.z;
        float y3 = acc[3][c] + xo.w;
        float4 yv = { y0, y1, y2, y3 };
        *(float4*)p = yv;
        red1[tr * DD + c0 + c] = y0 + y1 + y2 + y3;
        red2[tr * DD + c0 + c] = y0 * y0 + y1 * y1 + y2 * y2 + y3 * y3;
      }
    }
    __syncthreads();
    // column reduce -> per-GROUP stat shard (16-deep XCD-local atomic chains)
    if (tid < DD) {
      float t1 = 0.f;
#pragma unroll
      for (int q = 0; q < 16; ++q) t1 += red1[q * DD + tid];
      atomicAdd(&gstats[((size_t)l * NG + grp) * 128 + tid], t1);
    } else if (tid < 2 * DD) {
      int c = tid - DD;
      float t2 = 0.f;
#pragma unroll
      for (int q = 0; q < 16; ++q) t2 += red2[q * DD + c];
      atomicAdd(&gstats[((size_t)l * NG + grp) * 128 + DD + c], t2);
    }
    // restage wT for next MP layer from prefetched registers (wT dead since GEMM1)
    if (l < 2) {
#pragma unroll
      for (int j = 0; j < 4; ++j) {
        int e = (tid + j * 256) * 4;
        int r = e >> 6, k = e & 63;
        wT[(k + 0) * XP + r] = wreg[j].x;
        wT[(k + 1) * XP + r] = wreg[j].y;
        wT[(k + 2) * XP + r] = wreg[j].z;
        wT[(k + 3) * XP + r] = wreg[j].w;
      }
    }

    gbar(flags, l + 1);   // batch-global BN stats complete

    if (tid < DD) {
      float s1 = 0.f, s2 = 0.f;
#pragma unroll
      for (int g = 0; g < NG; ++g) {
        const float* p = gstats + ((size_t)l * NG + g) * 128;
        s1 += p[tid];
        s2 += p[DD + tid];
      }
      float mu  = s1 * (1.f / MT);
      float var = fmaxf(s2 * (1.f / MT) - mu * mu, 0.f);
      mus[tid] = mu;
      rss[tid] = rsqrtf(var + BN_EPS);
    }
    __syncthreads();

    // ---- normalize xsc in place; thread owns column d = tid>>2, quarter q ----
    {
      int d = tid >> 2, q = tid & 3;
      float mu = mus[d], rs = rss[d];
      float* p = xsc + d * XP + q * 16;
      float ps = 0.f;
#pragma unroll
      for (int w = 0; w < 4; ++w) {
        float4 v = *(const float4*)(p + w * 4);
        v.x = (v.x - mu) * rs; v.y = (v.y - mu) * rs;
        v.z = (v.z - mu) * rs; v.w = (v.w - mu) * rs;
        *(float4*)(p + w * 4) = v;
        ps += v.x + v.y + v.z + v.w;
      }
      poolp = ps;
    }
    if (l == 2) red1[tid] = poolp;   // pooling partials
    __syncthreads();
  }

  // ---- pool: mean over the 64 nodes of this graph -> mvec ----
  if (tid < DD)
    mvec[tid] = (red1[tid * 4] + red1[tid * 4 + 1] + red1[tid * 4 + 2] + red1[tid * 4 + 3])
                * (1.f / NPG);

  // ---- fused output MLP head: mol row is block-local; BN stats global ----
  // wTo overlays xsc (dead after pooling): 64*65 = 4160 <= XP*64 = 4352.
  float* wTo = xsc;
  float hn = 0.f;
  for (int j = 0; j < 2; ++j) {
    // stage Wo[j]^T via float4 (j==0 comes from the l==2 register prefetch)
#pragma unroll
    for (int q = 0; q < 4; ++q) {
      int e = (tid + q * 256) * 4;
      int r = e >> 6, k = e & 63;
      float4 wv = (j == 0) ? wreg[q] : *(const float4*)(Wo + 4096 + e);
      wTo[(k + 0) * 65 + r] = wv.x;
      wTo[(k + 1) * 65 + r] = wv.y;
      wTo[(k + 2) * 65 + r] = wv.z;
      wTo[(k + 3) * 65 + r] = wv.w;
    }
    __syncthreads();
    float h = 0.f;
    if (tid < DD) {
      float acc = bo[j * DD + tid];
#pragma unroll 8
      for (int k = 0; k < DD; ++k)
        acc += mvec[k] * wTo[k * 65 + tid];
      h = selu_f(acc);
      atomicAdd(&gstats[((size_t)(3 + j) * NG + grp) * 128 + tid], h);
      atomicAdd(&gstats[((size_t)(3 + j) * NG + grp) * 128 + DD + tid], h * h);
    }
    gbar(flags, 4 + j);   // head BN stats complete (over 128 graph rows)
    if (tid < DD) {
      float s1 = 0.f, s2 = 0.f;
#pragma unroll
      for (int g = 0; g < NG; ++g) {
        const float* p = gstats + ((size_t)(3 + j) * NG + g) * 128;
        s1 += p[tid];
        s2 += p[DD + tid];
      }
      float mu  = s1 * (1.f / NGRAPH);
      float var = fmaxf(s2 * (1.f / NGRAPH) - mu * mu, 0.f);
      hn = (h - mu) * rsqrtf(var + BN_EPS);
      if (j == 0) mvec[tid] = hn;   // feed next head layer (ordered by staging+sync)
    }
  }

  // ---- final projection: out[b] = dot(hn_row, Wp) + bp ----
  if (tid < DD) {
    float p = hn * Wp[tid];
#pragma unroll
    for (int o = 32; o; o >>= 1) p += __shfl_down(p, o, 64);
    if (tid == 0) out[b] = p + bp[0];
  }
}

extern "C" void kernel_launch(void* const* d_in, const int* in_sizes, int n_in,
                              void* d_out, int out_size, void* d_ws, size_t ws_size,
                              hipStream_t stream) {
  (void)in_sizes; (void)n_in; (void)out_size; (void)ws_size;
  const int*   fpr = (const int*)d_in[0];
  const float* adj = (const float*)d_in[1];
  const float* emb = (const float*)d_in[2];
  const float* Wf  = (const float*)d_in[3];
  const float* bfv = (const float*)d_in[4];
  const float* Wo  = (const float*)d_in[5];
  const float* bo  = (const float*)d_in[6];
  const float* Wp  = (const float*)d_in[7];
  const float* bp  = (const float*)d_in[8];

  float* ws     = (float*)d_ws;
  float* gstats = ws;                       // 5*NG*128 = 5120 floats
  int*   flags  = (int*)(ws + 5120);        // NBLK*FS = 4096 ints

  (void)hipMemsetAsync(ws, 0, (5120 + NBLK * FS) * sizeof(float), stream);

  gnn_k<<<NBLK, 256, 0, stream>>>(fpr, emb, adj, Wf, bfv, Wo, bo, Wp, bp,
                                  (float*)d_out, gstats, flags);
}